// Round 1
// baseline (4203.643 us; speedup 1.0000x reference)
//
#include <hip/hip_runtime.h>

#define BB 32
#define TT 256
#define INP 64
#define EE 128
#define DD 128
#define OO 32

// ---- workspace layout (float offsets) ----
#define OFF_XWF    0u          // B*T*512
#define OFF_XWB    4194304u    // B*T*512
#define OFF_HF     8388608u    // B*T*128
#define OFF_HBR    9437184u    // B*T*128
#define OFF_EP     10485760u   // B*128*T   (transposed [b][d][t], pre-scaled by 2*log2(e))
#define OFF_ENCW   11534336u   // B*T*512   packed [b][t4][j][4]
#define OFF_ENCWL  15728640u   // B*T*32    packed [b][t4][m][4]
#define OFF_ZC     15990784u   // B*512
#define OFF_WHHTF  16007168u   // 512*128 packed [k4][j][4]
#define OFF_WHHTB  16072704u
#define OFF_WIHTF  16138240u   // 512*64  packed [i4][j][4]
#define OFF_WIHTB  16171008u
#define OFF_WHHDT  16203776u   // 512*128 packed [k4][j][4]
#define OFF_WCAT   16269312u   // 256*672 packed [k4][j][4]  (cols: 128 Wa_e | 512 Wih_ctx | 32 Wl_ctx)
#define OFF_WAHT   16441344u   // 128*128 packed [k4][d][4]
#define OFF_WYT    16457728u   // 32*512  packed [m4][j][4]
#define OFF_WLHT   16474112u   // 128*32  packed [k4][m][4]
#define WS_FLOATS  16478208u   // ~62.9 MB

__device__ __forceinline__ float fexp2(float x){ return __builtin_amdgcn_exp2f(x); }
__device__ __forceinline__ float frcp(float x){ return __builtin_amdgcn_rcpf(x); }
__device__ __forceinline__ float fsig(float x){ return frcp(1.0f + fexp2(-1.4426950408889634f * x)); }
__device__ __forceinline__ float ftanh_(float x){ return 1.0f - 2.0f * frcp(1.0f + fexp2(2.8853900817779268f * x)); }

#define C2F 2.8853900817779268f
#define L2E 1.4426950408889634f

// ---------------- K0a: weight transposes / packing ----------------
__global__ void pack_kernel(const float* __restrict__ Whh_f, const float* __restrict__ Whh_b,
                            const float* __restrict__ Wih_f, const float* __restrict__ Wih_b,
                            const float* __restrict__ Whh_d, const float* __restrict__ Wa,
                            const float* __restrict__ Wih_d, const float* __restrict__ Wl,
                            float* __restrict__ ws){
  unsigned e = blockIdx.x * 256u + threadIdx.x;
  if (e < 65536u){ unsigned j=e>>7, k=e&127u; ws[OFF_WHHTF + (k>>2)*2048u + j*4u + (k&3u)] = Whh_f[e]; return; }
  e -= 65536u;
  if (e < 65536u){ unsigned j=e>>7, k=e&127u; ws[OFF_WHHTB + (k>>2)*2048u + j*4u + (k&3u)] = Whh_b[e]; return; }
  e -= 65536u;
  if (e < 32768u){ unsigned j=e>>6, i=e&63u; ws[OFF_WIHTF + (i>>2)*2048u + j*4u + (i&3u)] = Wih_f[e]; return; }
  e -= 32768u;
  if (e < 32768u){ unsigned j=e>>6, i=e&63u; ws[OFF_WIHTB + (i>>2)*2048u + j*4u + (i&3u)] = Wih_b[e]; return; }
  e -= 32768u;
  if (e < 65536u){ unsigned j=e>>7, k=e&127u; ws[OFF_WHHDT + (k>>2)*2048u + j*4u + (k&3u)] = Whh_d[e]; return; }
  e -= 65536u;
  if (e < 172032u){
    unsigned j = e >> 8, k = e & 255u;  // j<672, k<256
    float val;
    if (j < 128u)      val = Wa[j*384u + 128u + k];
    else if (j < 640u) val = Wih_d[(j-128u)*288u + 32u + k];
    else               val = Wl[(j-640u)*384u + 128u + k];
    ws[OFF_WCAT + (k>>2)*2688u + j*4u + (k&3u)] = val; return;
  }
  e -= 172032u;
  if (e < 16384u){ unsigned d=e>>7, k=e&127u; ws[OFF_WAHT + (k>>2)*512u + d*4u + (k&3u)] = Wa[d*384u + k]; return; }
  e -= 16384u;
  if (e < 16384u){ unsigned j=e>>5, m=e&31u; ws[OFF_WYT + (m>>2)*2048u + j*4u + (m&3u)] = Wih_d[j*288u + m]; return; }
  e -= 16384u;
  if (e < 4096u){ unsigned k=e>>5, m=e&31u; ws[OFF_WLHT + (k>>2)*128u + m*4u + (k&3u)] = Wl[m*384u + k]; return; }
}

// ---------------- K0b: zc[b][j] = b_d[j] + dec_h0[b] @ Whh_d[j,:] ----------------
__global__ __launch_bounds__(512) void zc_kernel(const float* __restrict__ dec_h0,
                                                 const float* __restrict__ b_d,
                                                 float* __restrict__ ws){
  __shared__ __align__(16) float h0[128];
  int b = blockIdx.x, j = threadIdx.x;
  if (j < 128) h0[j] = dec_h0[b*128 + j];
  __syncthreads();
  const float* WT = ws + OFF_WHHDT;
  float4 a4 = make_float4(0.f,0.f,0.f,0.f);
  #pragma unroll
  for (int k4 = 0; k4 < 32; k4++){
    float4 wv = *(const float4*)(WT + k4*2048 + j*4);
    float4 hv = *(const float4*)(h0 + k4*4);
    a4.x += wv.x*hv.x; a4.y += wv.y*hv.y; a4.z += wv.z*hv.z; a4.w += wv.w*hv.w;
  }
  ws[OFF_ZC + b*512 + j] = b_d[j] + (a4.x + a4.y) + (a4.z + a4.w);
}

// ---------------- K1: xW[dir][b][t][j] = bias[j] + x_row @ Wih[j,:] ----------------
__global__ __launch_bounds__(512) void xw_kernel(const float* __restrict__ x,
                                                 const int* __restrict__ lengths,
                                                 const float* __restrict__ b_f,
                                                 const float* __restrict__ b_b,
                                                 float* __restrict__ ws){
  int bx = blockIdx.x;
  int dir = bx >> 9, b = (bx >> 4) & 31, tile = bx & 15;
  int t0 = tile * 16;
  int len = lengths[b];
  __shared__ __align__(16) float xrow[16][64];
  const float* WT   = ws + (dir ? OFF_WIHTB : OFF_WIHTF);
  const float* bias = dir ? b_b : b_f;
  float* out = ws + (dir ? OFF_XWB : OFF_XWF) + (unsigned)b * TT * 512;
  int tid = threadIdx.x;
  for (int idx = tid; idx < 1024; idx += 512){
    int r = idx >> 6, i = idx & 63;
    int s = t0 + r;
    int src = dir ? ((s < len) ? (len - 1 - s) : 0) : s;
    xrow[r][i] = x[((unsigned)b * TT + src) * 64 + i];
  }
  __syncthreads();
  int j = tid;
  float bj = bias[j];
  float acc[16];
  #pragma unroll
  for (int r = 0; r < 16; r++) acc[r] = bj;
  #pragma unroll 4
  for (int i4 = 0; i4 < 16; i4++){
    float4 wv = *(const float4*)(WT + i4*2048 + j*4);
    #pragma unroll
    for (int r = 0; r < 16; r++){
      float4 xv = *(const float4*)(&xrow[r][i4*4]);
      acc[r] += wv.x*xv.x + wv.y*xv.y + wv.z*xv.z + wv.w*xv.w;
    }
  }
  #pragma unroll
  for (int r = 0; r < 16; r++) out[(t0 + r)*512 + j] = acc[r];
}

// ---------------- K2: LSTM recurrence, one block per (b, dir), Whh in registers ----------------
__global__ __launch_bounds__(512, 2) void lstm_kernel(const int* __restrict__ lengths,
                                                      float* __restrict__ ws){
  int bx = blockIdx.x;
  int b = bx & 31, dir = bx >> 5;
  int len = lengths[b];
  if (len < 1) len = 1; if (len > TT) len = TT;
  const float* xW = ws + (dir ? OFF_XWB : OFF_XWF) + (unsigned)b * TT * 512;
  const float* WT = ws + (dir ? OFF_WHHTB : OFF_WHHTF);
  float* hout = ws + (dir ? OFF_HBR : OFF_HF) + (unsigned)b * TT * 128;
  __shared__ __align__(16) float hsh[128];
  __shared__ __align__(16) float csh[128];
  __shared__ __align__(16) float zsh[512];
  int j = threadIdx.x;
  float w[128];
  #pragma unroll
  for (int k4 = 0; k4 < 32; k4++){
    float4 wv = *(const float4*)(WT + k4*2048 + j*4);
    w[k4*4+0] = wv.x; w[k4*4+1] = wv.y; w[k4*4+2] = wv.z; w[k4*4+3] = wv.w;
  }
  if (j < 128){ hsh[j] = 0.f; csh[j] = 0.f; }
  for (int t = 0; t < len; t++){
    __syncthreads();
    float4 a4 = make_float4(xW[t*512 + j], 0.f, 0.f, 0.f);
    #pragma unroll
    for (int k4 = 0; k4 < 32; k4++){
      float4 hv = *(const float4*)(hsh + k4*4);
      a4.x += w[k4*4+0]*hv.x; a4.y += w[k4*4+1]*hv.y;
      a4.z += w[k4*4+2]*hv.z; a4.w += w[k4*4+3]*hv.w;
    }
    zsh[j] = (a4.x + a4.y) + (a4.z + a4.w);
    __syncthreads();
    if (j < 128){
      float zi = zsh[j], zf = zsh[128+j], zg = zsh[256+j], zo = zsh[384+j];
      float c = fsig(zf)*csh[j] + fsig(zi)*ftanh_(zg);
      float h = fsig(zo)*ftanh_(c);
      csh[j] = c; hsh[j] = h;
      hout[t*128 + j] = h;
    }
  }
}

// ---------------- K3: enc = [hf,hb]; fused GEMM -> epT (scaled), encW, encWl ----------------
__global__ __launch_bounds__(192) void proj_kernel(const int* __restrict__ lengths,
                                                   const float* __restrict__ ba,
                                                   float* __restrict__ ws){
  int bx = blockIdx.x;
  int b = bx >> 4, tile = bx & 15;
  int len = lengths[b];
  if (len < 1) len = 1; if (len > TT) len = TT;
  int t0 = tile * 16;
  if (t0 >= len) return;
  __shared__ __align__(16) float enc[16][256];
  int tid = threadIdx.x;
  const float* hf  = ws + OFF_HF  + (unsigned)b * TT * 128;
  const float* hbr = ws + OFF_HBR + (unsigned)b * TT * 128;
  for (int idx = tid; idx < 4096; idx += 192){
    int r = idx >> 8, k = idx & 255;
    int t = t0 + r;
    float vv = 0.f;
    if (t < len) vv = (k < 128) ? hf[t*128 + k] : hbr[(len-1-t)*128 + (k-128)];
    enc[r][k] = vv;
  }
  __syncthreads();
  if (tid >= 168) return;
  int j0 = tid * 4;
  float acc[16][4];
  #pragma unroll
  for (int r = 0; r < 16; r++){ acc[r][0]=0.f; acc[r][1]=0.f; acc[r][2]=0.f; acc[r][3]=0.f; }
  const float* WC = ws + OFF_WCAT;
  for (int k4 = 0; k4 < 64; k4++){
    float4 w0 = *(const float4*)(WC + k4*2688 + (j0+0)*4);
    float4 w1 = *(const float4*)(WC + k4*2688 + (j0+1)*4);
    float4 w2 = *(const float4*)(WC + k4*2688 + (j0+2)*4);
    float4 w3 = *(const float4*)(WC + k4*2688 + (j0+3)*4);
    #pragma unroll
    for (int r = 0; r < 16; r++){
      float4 ev = *(const float4*)(&enc[r][k4*4]);
      acc[r][0] += w0.x*ev.x + w0.y*ev.y + w0.z*ev.z + w0.w*ev.w;
      acc[r][1] += w1.x*ev.x + w1.y*ev.y + w1.z*ev.z + w1.w*ev.w;
      acc[r][2] += w2.x*ev.x + w2.y*ev.y + w2.z*ev.z + w2.w*ev.w;
      acc[r][3] += w3.x*ev.x + w3.y*ev.y + w3.z*ev.z + w3.w*ev.w;
    }
  }
  float* epo  = ws + OFF_EP    + (unsigned)b * 128 * TT;   // [d][t]
  float* eW   = ws + OFF_ENCW  + (unsigned)b * TT * 512;
  float* eWl  = ws + OFF_ENCWL + (unsigned)b * TT * 32;
  for (int r = 0; r < 16; r++){
    int t = t0 + r;
    if (t >= len) break;
    #pragma unroll
    for (int c = 0; c < 4; c++){
      int j = j0 + c;
      float val = acc[r][c];
      if (j < 128)      epo[j*TT + t] = (val + ba[j]) * C2F;
      else if (j < 640) eW[(t>>2)*2048 + (j-128)*4 + (t&3)] = val;
      else              eWl[(t>>2)*128 + (j-640)*4 + (t&3)] = val;
    }
  }
}

// ---------------- K4: attention decoder, one block per batch ----------------
__global__ __launch_bounds__(512, 2) void decoder_kernel(const int* __restrict__ lengths,
                                                         const float* __restrict__ dec_h0,
                                                         const float* __restrict__ dec_c0,
                                                         const float* __restrict__ v,
                                                         const float* __restrict__ bl,
                                                         float* __restrict__ ws,
                                                         float* __restrict__ out){
  int b = blockIdx.x;
  int len = lengths[b];
  if (len < 1) len = 1; if (len > TT) len = TT;
  int tid = threadIdx.x;
  __shared__ __align__(16) float hsh[128];
  __shared__ __align__(16) float c0sh[128];
  __shared__ __align__(16) float vqsh[256];   // per d: [2d]=C2*q_d (per step), [2d+1]=v_d
  __shared__ __align__(16) float ylds[32];
  __shared__ __align__(16) float qpart[512];
  __shared__ __align__(16) float spart[512];
  __shared__ __align__(16) float ash[256];
  __shared__ __align__(16) float zsh[512];
  __shared__ __align__(16) float ypart[256];
  __shared__ float redbuf[4], redbuf2[4], vsumsh;

  const float* epg   = ws + OFF_EP    + (unsigned)b * 128 * TT;
  const float* eWg   = ws + OFF_ENCW  + (unsigned)b * TT * 512;
  const float* eWlg  = ws + OFF_ENCWL + (unsigned)b * TT * 32;
  const float* zcg   = ws + OFF_ZC + b * 512;
  const float* WahTg = ws + OFF_WAHT;
  const float* WyTg  = ws + OFF_WYT;
  const float* WlhTg = ws + OFF_WLHT;
  float* outp = out + (unsigned)b * 8223;

  if (tid < 128){
    hsh[tid]  = dec_h0[b*128 + tid];
    c0sh[tid] = dec_c0[b*128 + tid];
    vqsh[2*tid+1] = v[tid];
  }
  if (tid < 32) ylds[tid] = 0.f;
  if (tid < 31) outp[tid] = 0.f;
  if (tid == 0){ float s = 0.f; for (int k = 0; k < 128; k++) s += v[k]; vsumsh = s; }
  int nt4 = (len + 3) >> 2;

  for (int t = 0; t < TT; t++){
    __syncthreads();
    // ---- Phase A: q = hidden @ Wa_h.T (partials over 4 k-ranges) ----
    {
      int d = tid & 127, p = tid >> 7;
      float4 q4 = make_float4(0.f,0.f,0.f,0.f);
      #pragma unroll
      for (int i = 0; i < 8; i++){
        int k4 = p*8 + i;
        float4 wv = *(const float4*)(WahTg + k4*512 + d*4);
        float4 hv = *(const float4*)(hsh + k4*4);
        q4.x += wv.x*hv.x; q4.y += wv.y*hv.y; q4.z += wv.z*hv.z; q4.w += wv.w*hv.w;
      }
      qpart[tid] = (q4.x + q4.y) + (q4.z + q4.w);
    }
    __syncthreads();
    if (tid < 128)
      vqsh[2*tid] = (qpart[tid] + qpart[128+tid] + qpart[256+tid] + qpart[384+tid]) * C2F;
    __syncthreads();
    // ---- Phase B: partial scores  P = sum_d v_d / (1 + exp(2(ep+q))) ----
    {
      int t1 = tid >> 1, half = tid & 1;
      float4 P4 = make_float4(0.f,0.f,0.f,0.f);
      if (t1 < len){
        const float* ec = epg + (half*64) * TT + t1;
        const float* vq = vqsh + half*128;
        #pragma unroll 4
        for (int di = 0; di < 64; di += 4){
          float e0 = ec[(di+0)*TT], e1 = ec[(di+1)*TT];
          float e2 = ec[(di+2)*TT], e3 = ec[(di+3)*TT];
          float4 a01 = *(const float4*)(vq + di*2);
          float4 a23 = *(const float4*)(vq + di*2 + 4);
          P4.x = fmaf(a01.y, frcp(1.f + fexp2(e0 + a01.x)), P4.x);
          P4.y = fmaf(a01.w, frcp(1.f + fexp2(e1 + a01.z)), P4.y);
          P4.z = fmaf(a23.y, frcp(1.f + fexp2(e2 + a23.x)), P4.z);
          P4.w = fmaf(a23.w, frcp(1.f + fexp2(e3 + a23.z)), P4.w);
        }
      }
      spart[tid] = (P4.x + P4.y) + (P4.z + P4.w);
    }
    __syncthreads();
    // ---- Phase C: softmax over t' ----
    float sv = -1e30f, ex = 0.f;
    if (tid < 256 && tid < len) sv = vsumsh - 2.f * (spart[2*tid] + spart[2*tid+1]);
    {
      float m = sv;
      #pragma unroll
      for (int off = 32; off; off >>= 1) m = fmaxf(m, __shfl_xor(m, off));
      if (tid < 256 && (tid & 63) == 0) redbuf[tid>>6] = m;
    }
    __syncthreads();
    {
      float gm = fmaxf(fmaxf(redbuf[0], redbuf[1]), fmaxf(redbuf[2], redbuf[3]));
      if (tid < 256 && tid < len) ex = fexp2((sv - gm) * L2E);
      float ss = ex;
      #pragma unroll
      for (int off = 32; off; off >>= 1) ss += __shfl_xor(ss, off);
      if (tid < 256 && (tid & 63) == 0) redbuf2[tid>>6] = ss;
    }
    __syncthreads();
    if (tid < 256){
      float l = redbuf2[0] + redbuf2[1] + redbuf2[2] + redbuf2[3];
      ash[tid] = ex * frcp(l);
    }
    __syncthreads();
    // ---- Phase D: z = zc + a@encW + y@Wih_y.T ----
    {
      float4 a4 = make_float4(zcg[tid], 0.f, 0.f, 0.f);
      #pragma unroll 4
      for (int t4 = 0; t4 < nt4; t4++){
        float4 av = *(const float4*)(ash + t4*4);
        float4 wv = *(const float4*)(eWg + t4*2048 + tid*4);
        a4.x += av.x*wv.x; a4.y += av.y*wv.y; a4.z += av.z*wv.z; a4.w += av.w*wv.w;
      }
      #pragma unroll
      for (int m4 = 0; m4 < 8; m4++){
        float4 yv = *(const float4*)(ylds + m4*4);
        float4 wv = *(const float4*)(WyTg + m4*2048 + tid*4);
        a4.x += yv.x*wv.x; a4.y += yv.y*wv.y; a4.z += yv.z*wv.z; a4.w += yv.w*wv.w;
      }
      zsh[tid] = (a4.x + a4.y) + (a4.z + a4.w);
    }
    __syncthreads();
    // ---- Phase E: gates (dec_c0 is constant per the reference) ----
    if (tid < 128){
      float zi = zsh[tid], zf = zsh[128+tid], zg = zsh[256+tid], zo = zsh[384+tid];
      float c = fsig(zf)*c0sh[tid] + fsig(zi)*ftanh_(zg);
      hsh[tid] = fsig(zo)*ftanh_(c);
    }
    __syncthreads();
    // ---- Phase F: y_new = h@Wl_h.T + a@encWl + bl ----
    if (tid < 256){
      int m = tid & 31, p = tid >> 5;
      float acc = 0.f;
      for (int t4 = p; t4 < nt4; t4 += 8){
        float4 av = *(const float4*)(ash + t4*4);
        float4 wv = *(const float4*)(eWlg + t4*128 + m*4);
        acc += av.x*wv.x + av.y*wv.y + av.z*wv.z + av.w*wv.w;
      }
      #pragma unroll
      for (int k4 = p; k4 < 32; k4 += 8){
        float4 hv = *(const float4*)(hsh + k4*4);
        float4 wv = *(const float4*)(WlhTg + k4*128 + m*4);
        acc += hv.x*wv.x + hv.y*wv.y + hv.z*wv.z + hv.w*wv.w;
      }
      ypart[p*32 + m] = acc;
    }
    __syncthreads();
    if (tid < 32){
      float y = bl[tid];
      #pragma unroll
      for (int p2 = 0; p2 < 8; p2++) y += ypart[p2*32 + tid];
      ylds[tid] = y;
      outp[31 + t*32 + tid] = y;
    }
  }
}

extern "C" void kernel_launch(void* const* d_in, const int* in_sizes, int n_in,
                              void* d_out, int out_size, void* d_ws, size_t ws_size,
                              hipStream_t stream){
  const float* x       = (const float*)d_in[0];
  const int*   lengths = (const int*)  d_in[1];
  const float* dec_h0  = (const float*)d_in[2];
  const float* dec_c0  = (const float*)d_in[3];
  const float* Wih_f   = (const float*)d_in[4];
  const float* Whh_f   = (const float*)d_in[5];
  const float* b_f     = (const float*)d_in[6];
  const float* Wih_b   = (const float*)d_in[7];
  const float* Whh_b   = (const float*)d_in[8];
  const float* b_b     = (const float*)d_in[9];
  const float* Wa      = (const float*)d_in[10];
  const float* ba      = (const float*)d_in[11];
  const float* v       = (const float*)d_in[12];
  const float* Wih_d   = (const float*)d_in[13];
  const float* Whh_d   = (const float*)d_in[14];
  const float* b_d     = (const float*)d_in[15];
  const float* Wl      = (const float*)d_in[16];
  const float* bl      = (const float*)d_in[17];
  float* ws  = (float*)d_ws;
  float* out = (float*)d_out;

  pack_kernel<<<1840, 256, 0, stream>>>(Whh_f, Whh_b, Wih_f, Wih_b, Whh_d, Wa, Wih_d, Wl, ws);
  zc_kernel<<<32, 512, 0, stream>>>(dec_h0, b_d, ws);
  xw_kernel<<<1024, 512, 0, stream>>>(x, lengths, b_f, b_b, ws);
  lstm_kernel<<<64, 512, 0, stream>>>(lengths, ws);
  proj_kernel<<<512, 192, 0, stream>>>(lengths, ba, ws);
  decoder_kernel<<<32, 512, 0, stream>>>(lengths, dec_h0, dec_c0, v, bl, ws, out);
}

// Round 2
// 1987.573 us; speedup vs baseline: 2.1150x; 2.1150x over previous
//
#include <hip/hip_runtime.h>

#define BB 32
#define TT 256
#define INP 64
#define EE 128
#define DD 128
#define OO 32

// ---- workspace layout (float offsets) ----
// ENCWH aliases XWF; EPT/ENCWLH alias XWB (stream-ordered: xw -> lstm consumes XW,
// then proj writes EPT/ENCWH/ENCWLH, then decoder reads them).
#define OFF_XWF    0u          // B*T*512 staging (xw -> lstm)
#define OFF_ENCWH  0u          // B*128*512 half2-as-float (proj -> decoder)
#define OFF_XWB    4194304u    // B*T*512 staging
#define OFF_EPT    4194304u    // B*256*128 fp32, t-major, pre-scaled by 2*log2e
#define OFF_ENCWLH 5242880u    // B*128*32 half2-as-float
#define OFF_HF     8388608u    // B*T*128
#define OFF_HBR    9437184u    // B*T*128
#define OFF_ZC     10485760u   // B*512
#define OFF_WHHTF  10502144u   // 512*128 packed [k4][j][4]
#define OFF_WHHTB  10567680u
#define OFF_WIHTF  10633216u   // 512*64  packed [i4][j][4]
#define OFF_WIHTB  10665984u
#define OFF_WHHDT  10698752u   // 512*128 packed [k4][j][4]
#define OFF_WCAT   10764288u   // 256*672 packed [k4][j][4]
#define OFF_WLHT   10936320u   // 128*32 packed [k4][m][4] fp32
#define OFF_WAHH   10940416u   // 128*64 half2 [d][k2]
#define OFF_WYH    10948608u   // 16*512 half2 [m2][j]

typedef _Float16 h2_t __attribute__((ext_vector_type(2)));

__device__ __forceinline__ float fexp2(float x){ return __builtin_amdgcn_exp2f(x); }
__device__ __forceinline__ float frcp(float x){ return __builtin_amdgcn_rcpf(x); }
__device__ __forceinline__ float fsig(float x){ return frcp(1.0f + fexp2(-1.4426950408889634f * x)); }
__device__ __forceinline__ float ftanh_(float x){ return 1.0f - 2.0f * frcp(1.0f + fexp2(2.8853900817779268f * x)); }
__device__ __forceinline__ float packh2(float a, float b){
  h2_t t; t.x = (_Float16)a; t.y = (_Float16)b; return __builtin_bit_cast(float, t);
}
__device__ __forceinline__ h2_t ash2(float f){ return __builtin_bit_cast(h2_t, f); }
__device__ __forceinline__ float fdot2_(float a, float b, float c){
  return __builtin_amdgcn_fdot2(ash2(a), ash2(b), c, false);
}

#define C2F 2.8853900817779268f
#define L2E 1.4426950408889634f

// ---------------- K0a: weight transposes / packing ----------------
__global__ void pack_kernel(const float* __restrict__ Whh_f, const float* __restrict__ Whh_b,
                            const float* __restrict__ Wih_f, const float* __restrict__ Wih_b,
                            const float* __restrict__ Whh_d, const float* __restrict__ Wa,
                            const float* __restrict__ Wih_d, const float* __restrict__ Wl,
                            float* __restrict__ ws){
  unsigned e = blockIdx.x * 256u + threadIdx.x;
  if (e < 65536u){ unsigned j=e>>7, k=e&127u; ws[OFF_WHHTF + (k>>2)*2048u + j*4u + (k&3u)] = Whh_f[e]; return; }
  e -= 65536u;
  if (e < 65536u){ unsigned j=e>>7, k=e&127u; ws[OFF_WHHTB + (k>>2)*2048u + j*4u + (k&3u)] = Whh_b[e]; return; }
  e -= 65536u;
  if (e < 32768u){ unsigned j=e>>6, i=e&63u; ws[OFF_WIHTF + (i>>2)*2048u + j*4u + (i&3u)] = Wih_f[e]; return; }
  e -= 32768u;
  if (e < 32768u){ unsigned j=e>>6, i=e&63u; ws[OFF_WIHTB + (i>>2)*2048u + j*4u + (i&3u)] = Wih_b[e]; return; }
  e -= 32768u;
  if (e < 65536u){ unsigned j=e>>7, k=e&127u; ws[OFF_WHHDT + (k>>2)*2048u + j*4u + (k&3u)] = Whh_d[e]; return; }
  e -= 65536u;
  if (e < 172032u){
    unsigned j = e >> 8, k = e & 255u;  // j<672, k<256
    float val;
    if (j < 128u)      val = Wa[j*384u + 128u + k];
    else if (j < 640u) val = Wih_d[(j-128u)*288u + 32u + k];
    else               val = Wl[(j-640u)*384u + 128u + k];
    ws[OFF_WCAT + (k>>2)*2688u + j*4u + (k&3u)] = val; return;
  }
  e -= 172032u;
  if (e < 4096u){ unsigned k=e>>5, m=e&31u; ws[OFF_WLHT + (k>>2)*128u + m*4u + (k&3u)] = Wl[m*384u + k]; return; }
  e -= 4096u;
  if (e < 8192u){ // WAHH [d][k2] fp16 pairs over k
    unsigned d = e >> 6, k2 = e & 63u;
    ws[OFF_WAHH + e] = packh2(Wa[d*384u + 2u*k2], Wa[d*384u + 2u*k2 + 1u]); return;
  }
  e -= 8192u;
  if (e < 8192u){ // WYH [m2][j] fp16 pairs over m (first 32 cols of Wih_d)
    unsigned m2 = e >> 9, j = e & 511u;
    ws[OFF_WYH + e] = packh2(Wih_d[j*288u + 2u*m2], Wih_d[j*288u + 2u*m2 + 1u]); return;
  }
}

// ---------------- K0b: zc[b][j] = b_d[j] + dec_h0[b] @ Whh_d[j,:] ----------------
__global__ __launch_bounds__(512) void zc_kernel(const float* __restrict__ dec_h0,
                                                 const float* __restrict__ b_d,
                                                 float* __restrict__ ws){
  __shared__ __align__(16) float h0[128];
  int b = blockIdx.x, j = threadIdx.x;
  if (j < 128) h0[j] = dec_h0[b*128 + j];
  __syncthreads();
  const float* WT = ws + OFF_WHHDT;
  float4 a4 = make_float4(0.f,0.f,0.f,0.f);
  #pragma unroll
  for (int k4 = 0; k4 < 32; k4++){
    float4 wv = *(const float4*)(WT + k4*2048 + j*4);
    float4 hv = *(const float4*)(h0 + k4*4);
    a4.x += wv.x*hv.x; a4.y += wv.y*hv.y; a4.z += wv.z*hv.z; a4.w += wv.w*hv.w;
  }
  ws[OFF_ZC + b*512 + j] = b_d[j] + (a4.x + a4.y) + (a4.z + a4.w);
}

// ---------------- K1: xW staging ----------------
__global__ __launch_bounds__(512) void xw_kernel(const float* __restrict__ x,
                                                 const int* __restrict__ lengths,
                                                 const float* __restrict__ b_f,
                                                 const float* __restrict__ b_b,
                                                 float* __restrict__ ws){
  int bx = blockIdx.x;
  int dir = bx >> 9, b = (bx >> 4) & 31, tile = bx & 15;
  int t0 = tile * 16;
  int len = lengths[b];
  __shared__ __align__(16) float xrow[16][64];
  const float* WT   = ws + (dir ? OFF_WIHTB : OFF_WIHTF);
  const float* bias = dir ? b_b : b_f;
  float* out = ws + (dir ? OFF_XWB : OFF_XWF) + (unsigned)b * TT * 512;
  int tid = threadIdx.x;
  for (int idx = tid; idx < 1024; idx += 512){
    int r = idx >> 6, i = idx & 63;
    int s = t0 + r;
    int src = dir ? ((s < len) ? (len - 1 - s) : 0) : s;
    xrow[r][i] = x[((unsigned)b * TT + src) * 64 + i];
  }
  __syncthreads();
  int j = tid;
  float bj = bias[j];
  float acc[16];
  #pragma unroll
  for (int r = 0; r < 16; r++) acc[r] = bj;
  #pragma unroll 4
  for (int i4 = 0; i4 < 16; i4++){
    float4 wv = *(const float4*)(WT + i4*2048 + j*4);
    #pragma unroll
    for (int r = 0; r < 16; r++){
      float4 xv = *(const float4*)(&xrow[r][i4*4]);
      acc[r] += wv.x*xv.x + wv.y*xv.y + wv.z*xv.z + wv.w*xv.w;
    }
  }
  #pragma unroll
  for (int r = 0; r < 16; r++) out[(t0 + r)*512 + j] = acc[r];
}

// ---------------- K2: LSTM recurrence ----------------
__global__ __launch_bounds__(512, 2) void lstm_kernel(const int* __restrict__ lengths,
                                                      float* __restrict__ ws){
  int bx = blockIdx.x;
  int b = bx & 31, dir = bx >> 5;
  int len = lengths[b];
  if (len < 1) len = 1; if (len > TT) len = TT;
  const float* xW = ws + (dir ? OFF_XWB : OFF_XWF) + (unsigned)b * TT * 512;
  const float* WT = ws + (dir ? OFF_WHHTB : OFF_WHHTF);
  float* hout = ws + (dir ? OFF_HBR : OFF_HF) + (unsigned)b * TT * 128;
  __shared__ __align__(16) float hsh[128];
  __shared__ __align__(16) float csh[128];
  __shared__ __align__(16) float zsh[512];
  int j = threadIdx.x;
  float w[128];
  #pragma unroll
  for (int k4 = 0; k4 < 32; k4++){
    float4 wv = *(const float4*)(WT + k4*2048 + j*4);
    w[k4*4+0] = wv.x; w[k4*4+1] = wv.y; w[k4*4+2] = wv.z; w[k4*4+3] = wv.w;
  }
  if (j < 128){ hsh[j] = 0.f; csh[j] = 0.f; }
  for (int t = 0; t < len; t++){
    __syncthreads();
    float4 a4 = make_float4(xW[t*512 + j], 0.f, 0.f, 0.f);
    #pragma unroll
    for (int k4 = 0; k4 < 32; k4++){
      float4 hv = *(const float4*)(hsh + k4*4);
      a4.x += w[k4*4+0]*hv.x; a4.y += w[k4*4+1]*hv.y;
      a4.z += w[k4*4+2]*hv.z; a4.w += w[k4*4+3]*hv.w;
    }
    zsh[j] = (a4.x + a4.y) + (a4.z + a4.w);
    __syncthreads();
    if (j < 128){
      float zi = zsh[j], zf = zsh[128+j], zg = zsh[256+j], zo = zsh[384+j];
      float c = fsig(zf)*csh[j] + fsig(zi)*ftanh_(zg);
      float h = fsig(zo)*ftanh_(c);
      csh[j] = c; hsh[j] = h;
      hout[t*128 + j] = h;
    }
  }
}

// ---------------- K3: enc projections -> EPT (t-major fp32), ENCWH/ENCWLH (fp16 pairs) ----------------
__global__ __launch_bounds__(192) void proj_kernel(const int* __restrict__ lengths,
                                                   const float* __restrict__ ba,
                                                   float* __restrict__ ws){
  int bx = blockIdx.x;
  int b = bx >> 4, tile = bx & 15;
  int len = lengths[b];
  if (len < 1) len = 1; if (len > TT) len = TT;
  int t0 = tile * 16;
  __shared__ __align__(16) float enc[16][256];
  int tid = threadIdx.x;
  const float* hf  = ws + OFF_HF  + (unsigned)b * TT * 128;
  const float* hbr = ws + OFF_HBR + (unsigned)b * TT * 128;
  for (int idx = tid; idx < 4096; idx += 192){
    int r = idx >> 8, k = idx & 255;
    int t = t0 + r;
    float vv = 0.f;
    if (t < len) vv = (k < 128) ? hf[t*128 + k] : hbr[(len-1-t)*128 + (k-128)];
    enc[r][k] = vv;
  }
  __syncthreads();
  if (tid >= 168) return;
  int j0 = tid * 4;
  float acc[16][4];
  #pragma unroll
  for (int r = 0; r < 16; r++){ acc[r][0]=0.f; acc[r][1]=0.f; acc[r][2]=0.f; acc[r][3]=0.f; }
  const float* WC = ws + OFF_WCAT;
  for (int k4 = 0; k4 < 64; k4++){
    float4 w0 = *(const float4*)(WC + k4*2688 + (j0+0)*4);
    float4 w1 = *(const float4*)(WC + k4*2688 + (j0+1)*4);
    float4 w2 = *(const float4*)(WC + k4*2688 + (j0+2)*4);
    float4 w3 = *(const float4*)(WC + k4*2688 + (j0+3)*4);
    #pragma unroll
    for (int r = 0; r < 16; r++){
      float4 ev = *(const float4*)(&enc[r][k4*4]);
      acc[r][0] += w0.x*ev.x + w0.y*ev.y + w0.z*ev.z + w0.w*ev.w;
      acc[r][1] += w1.x*ev.x + w1.y*ev.y + w1.z*ev.z + w1.w*ev.w;
      acc[r][2] += w2.x*ev.x + w2.y*ev.y + w2.z*ev.z + w2.w*ev.w;
      acc[r][3] += w3.x*ev.x + w3.y*ev.y + w3.z*ev.z + w3.w*ev.w;
    }
  }
  float* epo  = ws + OFF_EPT    + (unsigned)b * TT * 128;   // [t][d]
  float* eWh  = ws + OFF_ENCWH  + (unsigned)b * 128 * 512;  // [t2][j] half2
  float* eWlh = ws + OFF_ENCWLH + (unsigned)b * 128 * 32;   // [t2][m] half2
  #pragma unroll
  for (int c = 0; c < 4; c++){
    int j = j0 + c;
    if (j < 128){
      float bj = ba[j];
      for (int r = 0; r < 16; r++) epo[(t0 + r)*128 + j] = (acc[r][c] + bj) * C2F;
    } else if (j < 640){
      for (int r2 = 0; r2 < 8; r2++)
        eWh[(tile*8 + r2)*512 + (j - 128)] = packh2(acc[2*r2][c], acc[2*r2+1][c]);
    } else {
      for (int r2 = 0; r2 < 8; r2++)
        eWlh[(tile*8 + r2)*32 + (j - 640)] = packh2(acc[2*r2][c], acc[2*r2+1][c]);
    }
  }
}

// ---------------- K4: attention decoder ----------------
// encW (fp16 pairs) held in 128 VGPRs/thread; Wa_h/Wy fp16 in 32 VGPRs; ep fp32 in LDS.
__global__ __launch_bounds__(512, 2) void decoder_kernel(const int* __restrict__ lengths,
                                                         const float* __restrict__ dec_h0,
                                                         const float* __restrict__ dec_c0,
                                                         const float* __restrict__ v,
                                                         const float* __restrict__ bl,
                                                         float* __restrict__ ws,
                                                         float* __restrict__ out){
  __shared__ __align__(16) float ep_lds[32768];   // [t][(d+4t)&127]
  __shared__ __align__(16) float red512[512];
  __shared__ __align__(16) float zsh[512];
  __shared__ __align__(16) float vqsh[256];       // [2d]=C2F*q_d, [2d+1]=v_d
  __shared__ __align__(16) float hsh[128];
  __shared__ __align__(16) float c0sh[128];
  __shared__ __align__(16) float a_h2[128];       // half2 pairs of a over t
  __shared__ __align__(16) float h_h2[64];        // half2 pairs of h over k
  __shared__ __align__(16) float ylds[32];
  __shared__ __align__(16) float y_h2[16];
  __shared__ float redbuf[2], redbuf2[2], vsumsh;

  int b = blockIdx.x;
  int len = lengths[b];
  if (len < 1) len = 1; if (len > TT) len = TT;
  int tid = threadIdx.x;

  const float* EPT  = ws + OFF_EPT    + (unsigned)b * 32768;
  const float* EWH  = ws + OFF_ENCWH  + (unsigned)b * 65536;
  const float* EWLH = ws + OFF_ENCWLH + (unsigned)b * 4096;
  const float* WLHT = ws + OFF_WLHT;
  float* outp = out + (unsigned)b * 8223;

  // persistent register-resident operands
  float wreg[128];
  #pragma unroll
  for (int r = 0; r < 128; r++) wreg[r] = EWH[r*512 + tid];
  int d_ = tid & 127, p_ = tid >> 7;
  float wah[16];
  #pragma unroll
  for (int i = 0; i < 16; i++) wah[i] = ws[OFF_WAHH + d_*64 + p_*16 + i];
  float wy[16];
  #pragma unroll
  for (int i = 0; i < 16; i++) wy[i] = ws[OFF_WYH + i*512 + tid];
  float zc_r = ws[OFF_ZC + b*512 + tid];

  // ep -> LDS (swizzled)
  for (int c = 0; c < 64; c++){
    int idx = c*512 + tid;
    int t = idx >> 7, dd = idx & 127;
    ep_lds[t*128 + ((dd + 4*t) & 127)] = EPT[idx];
  }
  if (tid < 128){
    hsh[tid]  = dec_h0[b*128 + tid];
    c0sh[tid] = dec_c0[b*128 + tid];
    vqsh[2*tid+1] = v[tid];
  }
  if (tid < 64) h_h2[tid] = packh2(dec_h0[b*128 + 2*tid], dec_h0[b*128 + 2*tid + 1]);
  if (tid < 32) ylds[tid] = 0.f;
  if (tid < 16) y_h2[tid] = 0.f;
  if (tid < 31) outp[tid] = 0.f;
  if (tid == 0){ float s = 0.f; for (int k = 0; k < 128; k++) s += v[k]; vsumsh = s; }

  for (int t = 0; t < TT; t++){
    __syncthreads();
    // pack prev y to half2 (ylds written before the barrier above)
    if (tid < 16) y_h2[tid] = packh2(ylds[2*tid], ylds[2*tid+1]);
    // ---- Phase A: q_d partials via fp16 dot2 (Wa_h in regs, h in LDS) ----
    {
      float qa = 0.f, qb = 0.f;
      #pragma unroll
      for (int i = 0; i < 16; i += 2){
        qa = fdot2_(h_h2[p_*16 + i],     wah[i],     qa);
        qb = fdot2_(h_h2[p_*16 + i + 1], wah[i + 1], qb);
      }
      red512[tid] = qa + qb;
    }
    __syncthreads();
    if (tid < 128)
      vqsh[2*tid] = (red512[tid] + red512[128+tid] + red512[256+tid] + red512[384+tid]) * C2F;
    __syncthreads();
    // ---- Phase B: partial scores from LDS ep ----
    {
      int tt = tid & 255, half = tid >> 8;
      float4 P4 = make_float4(0.f,0.f,0.f,0.f);
      if (tt < len){
        const float* epr = ep_lds + tt*128;
        int rot = 4*tt;
        #pragma unroll 4
        for (int g = 0; g < 16; g++){
          int d0 = (half*16 + g)*4;
          float4 e4 = *(const float4*)(epr + ((d0 + rot) & 127));
          float4 vq0 = *(const float4*)(vqsh + 2*d0);
          float4 vq1 = *(const float4*)(vqsh + 2*d0 + 4);
          P4.x = fmaf(vq0.y, frcp(1.f + fexp2(e4.x + vq0.x)), P4.x);
          P4.y = fmaf(vq0.w, frcp(1.f + fexp2(e4.y + vq0.z)), P4.y);
          P4.z = fmaf(vq1.y, frcp(1.f + fexp2(e4.z + vq1.x)), P4.z);
          P4.w = fmaf(vq1.w, frcp(1.f + fexp2(e4.w + vq1.z)), P4.w);
        }
      }
      red512[tid] = (P4.x + P4.y) + (P4.z + P4.w);
    }
    __syncthreads();
    // ---- Phase C: softmax; thread tid<128 owns t-pair (2tid, 2tid+1) ----
    float s0 = -1e30f, s1 = -1e30f, e0 = 0.f, e1 = 0.f;
    if (tid < 128){
      int ta = 2*tid;
      if (ta < len)     s0 = vsumsh - 2.f*(red512[ta]   + red512[256+ta]);
      if (ta + 1 < len) s1 = vsumsh - 2.f*(red512[ta+1] + red512[256+ta+1]);
    }
    {
      float mm = fmaxf(s0, s1);
      #pragma unroll
      for (int off = 32; off; off >>= 1) mm = fmaxf(mm, __shfl_xor(mm, off));
      if (tid < 128 && (tid & 63) == 0) redbuf[tid>>6] = mm;
    }
    __syncthreads();
    if (tid < 128){
      float gm = fmaxf(redbuf[0], redbuf[1]);
      if (2*tid < len)     e0 = fexp2((s0 - gm) * L2E);
      if (2*tid + 1 < len) e1 = fexp2((s1 - gm) * L2E);
    }
    {
      float ss = e0 + e1;
      #pragma unroll
      for (int off = 32; off; off >>= 1) ss += __shfl_xor(ss, off);
      if (tid < 128 && (tid & 63) == 0) redbuf2[tid>>6] = ss;
    }
    __syncthreads();
    if (tid < 128){
      float rl = frcp(redbuf2[0] + redbuf2[1]);
      a_h2[tid] = packh2(e0 * rl, e1 * rl);
    }
    __syncthreads();
    // ---- Phase D: z_j = zc_j + a.encW(:,j) + y.Wy(:,j)  (all fp16 dot2, regs) ----
    {
      float za = 0.f, zb = 0.f, zc2 = 0.f, zd = 0.f;
      #pragma unroll
      for (int r4 = 0; r4 < 32; r4++){
        za  = fdot2_(a_h2[4*r4+0], wreg[4*r4+0], za);
        zb  = fdot2_(a_h2[4*r4+1], wreg[4*r4+1], zb);
        zc2 = fdot2_(a_h2[4*r4+2], wreg[4*r4+2], zc2);
        zd  = fdot2_(a_h2[4*r4+3], wreg[4*r4+3], zd);
      }
      #pragma unroll
      for (int i4 = 0; i4 < 4; i4++){
        za  = fdot2_(y_h2[4*i4+0], wy[4*i4+0], za);
        zb  = fdot2_(y_h2[4*i4+1], wy[4*i4+1], zb);
        zc2 = fdot2_(y_h2[4*i4+2], wy[4*i4+2], zc2);
        zd  = fdot2_(y_h2[4*i4+3], wy[4*i4+3], zd);
      }
      zsh[tid] = zc_r + ((za + zb) + (zc2 + zd));
    }
    __syncthreads();
    // ---- Phase E: gates (c0 constant per reference) ----
    if (tid < 128){
      float zi = zsh[tid], zf = zsh[128+tid], zg = zsh[256+tid], zo = zsh[384+tid];
      float c = fsig(zf)*c0sh[tid] + fsig(zi)*ftanh_(zg);
      hsh[tid] = fsig(zo)*ftanh_(c);
    }
    __syncthreads();
    // pack h to half2 (idle lanes), in parallel with Phase F
    if (tid >= 256 && tid < 320){
      int i = tid - 256;
      h_h2[i] = packh2(hsh[2*i], hsh[2*i+1]);
    }
    // ---- Phase F: y = a.eWl + h.Wl_h + bl ----
    if (tid < 256){
      int m = tid & 31, p = tid >> 5;
      float acc = 0.f;
      #pragma unroll
      for (int ri = 0; ri < 16; ri++){
        int r = p + ri*8;
        acc = fdot2_(a_h2[r], EWLH[r*32 + m], acc);
      }
      #pragma unroll
      for (int k4 = p; k4 < 32; k4 += 8){
        float4 hv = *(const float4*)(hsh + k4*4);
        float4 wv = *(const float4*)(WLHT + k4*128 + m*4);
        acc += hv.x*wv.x + hv.y*wv.y + hv.z*wv.z + hv.w*wv.w;
      }
      red512[tid] = acc;
    }
    __syncthreads();
    if (tid < 32){
      float y = bl[tid];
      #pragma unroll
      for (int p2 = 0; p2 < 8; p2++) y += red512[p2*32 + tid];
      ylds[tid] = y;
      outp[31 + t*32 + tid] = y;
    }
  }
}

extern "C" void kernel_launch(void* const* d_in, const int* in_sizes, int n_in,
                              void* d_out, int out_size, void* d_ws, size_t ws_size,
                              hipStream_t stream){
  const float* x       = (const float*)d_in[0];
  const int*   lengths = (const int*)  d_in[1];
  const float* dec_h0  = (const float*)d_in[2];
  const float* dec_c0  = (const float*)d_in[3];
  const float* Wih_f   = (const float*)d_in[4];
  const float* Whh_f   = (const float*)d_in[5];
  const float* b_f     = (const float*)d_in[6];
  const float* Wih_b   = (const float*)d_in[7];
  const float* Whh_b   = (const float*)d_in[8];
  const float* b_b     = (const float*)d_in[9];
  const float* Wa      = (const float*)d_in[10];
  const float* ba      = (const float*)d_in[11];
  const float* v       = (const float*)d_in[12];
  const float* Wih_d   = (const float*)d_in[13];
  const float* Whh_d   = (const float*)d_in[14];
  const float* b_d     = (const float*)d_in[15];
  const float* Wl      = (const float*)d_in[16];
  const float* bl      = (const float*)d_in[17];
  float* ws  = (float*)d_ws;
  float* out = (float*)d_out;

  pack_kernel<<<1776, 256, 0, stream>>>(Whh_f, Whh_b, Wih_f, Wih_b, Whh_d, Wa, Wih_d, Wl, ws);
  zc_kernel<<<32, 512, 0, stream>>>(dec_h0, b_d, ws);
  xw_kernel<<<1024, 512, 0, stream>>>(x, lengths, b_f, b_b, ws);
  lstm_kernel<<<64, 512, 0, stream>>>(lengths, ws);
  proj_kernel<<<512, 192, 0, stream>>>(lengths, ba, ws);
  decoder_kernel<<<32, 512, 0, stream>>>(lengths, dec_h0, dec_c0, v, bl, ws, out);
}